// Round 5
// baseline (358.116 us; speedup 1.0000x reference)
//
#include <hip/hip_runtime.h>

#define CC 64      // channels
#define SS 16384   // D*W*H
#define NN 65536   // B*S tokens
#define KK 2048    // codebook size
#define BM 64      // tokens per block tile
#define BK 64      // codes per k-tile (argmin) — 2-way (free) LDS reads

// ============ kernel 1: pre = W_in @ x + b_in (fp64 accum, 4x4 tile) =====
__global__ __launch_bounds__(256, 4) void vq_conv_in(
    const float* __restrict__ x, const float* __restrict__ w_in,
    const float* __restrict__ b_in, float* __restrict__ xf) {
  __shared__ float xs[CC][BM];  // xs[ci][tok]
  __shared__ float wt[CC][CC];  // wt[ci][o] = w_in[o][ci]
  int t = threadIdx.x;
  int n0 = blockIdx.x * BM;
  int b = n0 >> 14, s0 = n0 & (SS - 1);
  {  // stage wt transposed: thread -> one o-row, 16 ci
    int o = t >> 2, c0 = (t & 3) * 16;
    const float4* wr = (const float4*)(w_in + o * CC + c0);
#pragma unroll
    for (int i = 0; i < 4; ++i) {
      float4 v = wr[i];
      int ci = c0 + 4 * i;
      wt[ci + 0][o] = v.x; wt[ci + 1][o] = v.y;
      wt[ci + 2][o] = v.z; wt[ci + 3][o] = v.w;
    }
  }
#pragma unroll
  for (int i = 0; i < 4; ++i) {  // stage xs (coalesced rows)
    int e4 = t + 256 * i;
    int ci = e4 >> 4, tok4 = (e4 & 15) * 4;
    *(float4*)&xs[ci][tok4] =
        *(const float4*)(x + (size_t)b * CC * SS + (size_t)ci * SS + s0 + tok4);
  }
  __syncthreads();
  int tx = t & 15, ty = t >> 4;
  double acc[4][4];
#pragma unroll
  for (int j = 0; j < 4; ++j) {
    double bj = (double)b_in[tx * 4 + j];
#pragma unroll
    for (int m = 0; m < 4; ++m) acc[m][j] = bj;
  }
#pragma unroll 8
  for (int ci = 0; ci < CC; ++ci) {
    float4 xq = *(const float4*)&xs[ci][ty * 4];
    float4 wq = *(const float4*)&wt[ci][tx * 4];
    double xm[4] = {xq.x, xq.y, xq.z, xq.w};
    double wm[4] = {wq.x, wq.y, wq.z, wq.w};
#pragma unroll
    for (int m = 0; m < 4; ++m)
#pragma unroll
      for (int j = 0; j < 4; ++j) acc[m][j] = fma(xm[m], wm[j], acc[m][j]);
  }
#pragma unroll
  for (int j = 0; j < 4; ++j) {
    float4 ov = make_float4((float)acc[0][j], (float)acc[1][j],
                            (float)acc[2][j], (float)acc[3][j]);
    *(float4*)(xf + (size_t)b * CC * SS + (size_t)(tx * 4 + j) * SS + s0 +
               ty * 4) = ov;
  }
}

// ============ kernel 2: code norms ============
__global__ __launch_bounds__(256) void vq_cnorm(
    const float* __restrict__ cb, float* __restrict__ cnorm) {
  int k = blockIdx.x * 256 + threadIdx.x;
  const float4* r = (const float4*)(cb + (size_t)k * CC);
  float s = 0.f;
#pragma unroll
  for (int i = 0; i < 16; ++i) {
    float4 v = r[i];
    s = fmaf(v.x, v.x, s); s = fmaf(v.y, v.y, s);
    s = fmaf(v.z, v.z, s); s = fmaf(v.w, v.w, s);
  }
  cnorm[k] = s;
}

// ============ kernel 3: tiled argmin scan, BK=64, conflict-free reads ====
// Block: 64 tokens x 2048 codes (32 tiles of 64). Thread (ty,tx): 4 tokens
// x 4 codes (16 fp32 accs). ct read at tx*16B = 2-way bank alias (free).
// LDS 33KB -> 4 blocks/CU (16 waves) for latency hiding. Top-2 per 8-lane
// partition (2 partitions -> 4 candidates/token), fp64 re-rank downstream.
__global__ __launch_bounds__(256, 4) void vq_argmin(
    const float* __restrict__ xf, const float* __restrict__ cb,
    const float* __restrict__ cnorm, int* __restrict__ cidx) {
  __shared__ float xs[CC][BM];  // 16KB
  __shared__ float ct[CC][BK];  // 16KB, ct[ch][code]
  __shared__ float cnt[BK];
  int t = threadIdx.x;
  int n0 = blockIdx.x * BM;
  int b = n0 >> 14, s0 = n0 & (SS - 1);
#pragma unroll
  for (int i = 0; i < 4; ++i) {
    int e4 = t + 256 * i;
    int ci = e4 >> 4, tok4 = (e4 & 15) * 4;
    *(float4*)&xs[ci][tok4] = *(const float4*)(xf + (size_t)b * CC * SS +
                                               (size_t)ci * SS + s0 + tok4);
  }
  int tx = t & 15, ty = t >> 4;
  float best[4], secd[4];
  int bi[4], si[4];
#pragma unroll
  for (int m = 0; m < 4; ++m) {
    best[m] = 3.402823466e+38f; secd[m] = 3.402823466e+38f;
    bi[m] = 0; si[m] = 0;
  }
  for (int kt = 0; kt < KK; kt += BK) {
    {  // stage ct transposed: 4 threads share one code row (16 ch each)
      int code = t >> 2, c0 = (t & 3) * 16;
      const float4* cr = (const float4*)(cb + (size_t)(kt + code) * CC + c0);
#pragma unroll
      for (int i = 0; i < 4; ++i) {
        float4 v = cr[i];
        int ch = c0 + 4 * i;
        ct[ch + 0][code] = v.x; ct[ch + 1][code] = v.y;
        ct[ch + 2][code] = v.z; ct[ch + 3][code] = v.w;
      }
      if (t < BK / 4) *(float4*)&cnt[t * 4] = *(const float4*)(cnorm + kt + t * 4);
    }
    __syncthreads();
    float acc[4][4];
#pragma unroll
    for (int m = 0; m < 4; ++m)
#pragma unroll
      for (int j = 0; j < 4; ++j) acc[m][j] = 0.f;
#pragma unroll 8
    for (int c = 0; c < CC; ++c) {
      float4 xq = *(const float4*)&xs[c][ty * 4];
      float4 cv = *(const float4*)&ct[c][tx * 4];
      acc[0][0] = fmaf(xq.x, cv.x, acc[0][0]);
      acc[0][1] = fmaf(xq.x, cv.y, acc[0][1]);
      acc[0][2] = fmaf(xq.x, cv.z, acc[0][2]);
      acc[0][3] = fmaf(xq.x, cv.w, acc[0][3]);
      acc[1][0] = fmaf(xq.y, cv.x, acc[1][0]);
      acc[1][1] = fmaf(xq.y, cv.y, acc[1][1]);
      acc[1][2] = fmaf(xq.y, cv.z, acc[1][2]);
      acc[1][3] = fmaf(xq.y, cv.w, acc[1][3]);
      acc[2][0] = fmaf(xq.z, cv.x, acc[2][0]);
      acc[2][1] = fmaf(xq.z, cv.y, acc[2][1]);
      acc[2][2] = fmaf(xq.z, cv.z, acc[2][2]);
      acc[2][3] = fmaf(xq.z, cv.w, acc[2][3]);
      acc[3][0] = fmaf(xq.w, cv.x, acc[3][0]);
      acc[3][1] = fmaf(xq.w, cv.y, acc[3][1]);
      acc[3][2] = fmaf(xq.w, cv.z, acc[3][2]);
      acc[3][3] = fmaf(xq.w, cv.w, acc[3][3]);
    }
#pragma unroll
    for (int j = 0; j < 4; ++j) {
      int k = kt + tx * 4 + j;
      float cn = cnt[tx * 4 + j];
#pragma unroll
      for (int m = 0; m < 4; ++m) {
        float D = fmaf(-2.f, acc[m][j], cn);
        if (D < best[m]) {
          secd[m] = best[m]; si[m] = bi[m]; best[m] = D; bi[m] = k;
        } else if (D < secd[m]) {
          secd[m] = D; si[m] = k;
        }
      }
    }
    __syncthreads();  // protect ct before next tile's staging
  }
  // merge top-2 over each 8-lane group (xor 1,2,4 across tx bits), lex order
#pragma unroll
  for (int step = 1; step <= 4; step <<= 1) {
#pragma unroll
    for (int m = 0; m < 4; ++m) {
      float ob = __shfl_xor(best[m], step, 64);
      int oi = __shfl_xor(bi[m], step, 64);
      float os = __shfl_xor(secd[m], step, 64);
      int oj = __shfl_xor(si[m], step, 64);
      bool oW = (ob < best[m]) || (ob == best[m] && oi < bi[m]);
      float nb = oW ? ob : best[m];
      int ni = oW ? oi : bi[m];
      float lb = oW ? best[m] : ob;  // loser of best-compare
      int li = oW ? bi[m] : oi;
      float ws = oW ? os : secd[m];  // winner's second
      int wi = oW ? oj : si[m];
      bool sW = (ws < lb) || (ws == lb && wi < li);
      best[m] = nb; bi[m] = ni;
      secd[m] = sW ? ws : lb; si[m] = sW ? wi : li;
    }
  }
  if ((tx & 7) == 0) {
    int g = tx >> 3;
#pragma unroll
    for (int m = 0; m < 4; ++m) {
      int token = n0 + ty * 4 + m;
      cidx[(size_t)(g * 2 + 0) * NN + token] = bi[m];
      cidx[(size_t)(g * 2 + 1) * NN + token] = si[m];
    }
  }
}

// ============ kernel 4: exact fp64 select among 4 candidates ============
__global__ __launch_bounds__(256) void vq_select(
    const float* __restrict__ xf, const float* __restrict__ cb,
    const int* __restrict__ cidx, int* __restrict__ sel) {
  int t = threadIdx.x;
  int n = blockIdx.x * 64 + (t >> 2);
  int cand = t & 3;
  int b = n >> 14, s = n & (SS - 1);
  int kj = cidx[(size_t)cand * NN + n];
  const float* xp = xf + (size_t)b * CC * SS + s;
  const float* cp = cb + (size_t)kj * CC;
  double dj = 0.0;
#pragma unroll 8
  for (int c = 0; c < CC; ++c) {
    double df = (double)xp[(size_t)c * SS] - (double)cp[c];
    dj = fma(df, df, dj);
  }
#pragma unroll
  for (int step = 1; step <= 2; step <<= 1) {
    double od = __shfl_xor(dj, step, 64);
    int ok = __shfl_xor(kj, step, 64);
    if (od < dj || (od == dj && ok < kj)) { dj = od; kj = ok; }
  }
  if (cand == 0) sel[n] = kj;
}

// ====== kernel 5: gather q, z-write, losses, conv_out (4x4 tile) ======
__global__ __launch_bounds__(256, 3) void vq_finish(
    const float* __restrict__ cb, const float* __restrict__ w_out,
    const float* __restrict__ b_out, const int* __restrict__ sel,
    float* __restrict__ dout, float* __restrict__ loss_acc) {
  __shared__ float qs[CC][BM];
  __shared__ float xs[CC][BM];
  __shared__ float wt[CC][CC];
  __shared__ int ids[BM];
  int t = threadIdx.x;
  int n0 = blockIdx.x * BM;
  int b = n0 >> 14, s0 = n0 & (SS - 1);
  float* zreg = dout + (size_t)NN * CC;
  if (t < BM) ids[t] = sel[n0 + t];
  {  // stage wt transposed
    int o = t >> 2, c0 = (t & 3) * 16;
    const float4* wr = (const float4*)(w_out + o * CC + c0);
#pragma unroll
    for (int i = 0; i < 4; ++i) {
      float4 v = wr[i];
      int ci = c0 + 4 * i;
      wt[ci + 0][o] = v.x; wt[ci + 1][o] = v.y;
      wt[ci + 2][o] = v.z; wt[ci + 3][o] = v.w;
    }
  }
#pragma unroll
  for (int i = 0; i < 4; ++i) {  // stage xs (= xf) from z region
    int e4 = t + 256 * i;
    int ci = e4 >> 4, tok4 = (e4 & 15) * 4;
    *(float4*)&xs[ci][tok4] = *(const float4*)(zreg + (size_t)b * CC * SS +
                                               (size_t)ci * SS + s0 + tok4);
  }
  __syncthreads();  // ids ready
  {  // stage qs[ch][tok] = codebook[ids[tok]]
    int tok = t >> 2, c0 = (t & 3) * 16;
    const float4* qr = (const float4*)(cb + (size_t)ids[tok] * CC + c0);
#pragma unroll
    for (int i = 0; i < 4; ++i) {
      float4 v = qr[i];
      int ch = c0 + 4 * i;
      qs[ch + 0][tok] = v.x; qs[ch + 1][tok] = v.y;
      qs[ch + 2][tok] = v.z; qs[ch + 3][tok] = v.w;
    }
  }
  __syncthreads();
  // losses + z := q (coalesced float4 rows)
  float lsum = 0.f;
#pragma unroll
  for (int i = 0; i < 4; ++i) {
    int e4 = t + 256 * i;
    int ci = e4 >> 4, tok4 = (e4 & 15) * 4;
    float4 qv = *(const float4*)&qs[ci][tok4];
    float4 xv = *(const float4*)&xs[ci][tok4];
    float dx = qv.x - xv.x, dy = qv.y - xv.y;
    float dz = qv.z - xv.z, dw = qv.w - xv.w;
    lsum = fmaf(dx, dx, lsum); lsum = fmaf(dy, dy, lsum);
    lsum = fmaf(dz, dz, lsum); lsum = fmaf(dw, dw, lsum);
    *(float4*)(zreg + (size_t)b * CC * SS + (size_t)ci * SS + s0 + tok4) = qv;
  }
  // conv_out: 4 tok x 4 oc per thread
  int tx = t & 15, ty = t >> 4;
  float acc[4][4];
#pragma unroll
  for (int j = 0; j < 4; ++j) {
    float bj = b_out[tx * 4 + j];
#pragma unroll
    for (int m = 0; m < 4; ++m) acc[m][j] = bj;
  }
#pragma unroll 8
  for (int ci = 0; ci < CC; ++ci) {
    float4 xq = *(const float4*)&qs[ci][ty * 4];
    float4 wq = *(const float4*)&wt[ci][tx * 4];
    float xm[4] = {xq.x, xq.y, xq.z, xq.w};
    float wm[4] = {wq.x, wq.y, wq.z, wq.w};
#pragma unroll
    for (int m = 0; m < 4; ++m)
#pragma unroll
      for (int j = 0; j < 4; ++j) acc[m][j] = fmaf(xm[m], wm[j], acc[m][j]);
  }
#pragma unroll
  for (int j = 0; j < 4; ++j) {
    float4 ov = make_float4(acc[0][j], acc[1][j], acc[2][j], acc[3][j]);
    *(float4*)(dout + (size_t)b * CC * SS + (size_t)(tx * 4 + j) * SS + s0 +
               ty * 4) = ov;
  }
  // loss reduce: wave shuffle + one atomic per block
#pragma unroll
  for (int off = 32; off > 0; off >>= 1) lsum += __shfl_down(lsum, off, 64);
  __shared__ float wsum[4];
  if ((t & 63) == 0) wsum[t >> 6] = lsum;
  __syncthreads();
  if (t == 0) atomicAdd(loss_acc, wsum[0] + wsum[1] + wsum[2] + wsum[3]);
}

// ============ kernel 6: finalize scalar losses ============
__global__ void vq_finalize(const float* __restrict__ loss_acc,
                            float* __restrict__ dout) {
  float l = loss_acc[0] * (1.0f / (float)((size_t)NN * CC));
  dout[(size_t)2 * NN * CC + 0] = l;  // codebook_loss
  dout[(size_t)2 * NN * CC + 1] = l;  // commitment_loss
}

extern "C" void kernel_launch(void* const* d_in, const int* in_sizes, int n_in,
                              void* d_out, int out_size, void* d_ws,
                              size_t ws_size, hipStream_t stream) {
  const float* x = (const float*)d_in[0];
  const float* cb = (const float*)d_in[1];
  const float* w_in = (const float*)d_in[2];
  const float* b_in = (const float*)d_in[3];
  const float* w_out = (const float*)d_in[4];
  const float* b_out = (const float*)d_in[5];
  float* out = (float*)d_out;
  float* zreg = out + (size_t)NN * CC;  // z region doubles as xf scratch

  // ws: [0,4) loss; [1024,9216) cnorm; [16K,272K) sel; [512K,1.5M) cidx
  float* loss_acc = (float*)d_ws;
  float* cnorm = (float*)((char*)d_ws + 1024);
  int* sel = (int*)((char*)d_ws + 16384);
  int* cidx = (int*)((char*)d_ws + 524288);

  hipMemsetAsync(d_ws, 0, 4, stream);

  vq_conv_in<<<NN / BM, 256, 0, stream>>>(x, w_in, b_in, zreg);
  vq_cnorm<<<KK / 256, 256, 0, stream>>>(cb, cnorm);
  vq_argmin<<<NN / BM, 256, 0, stream>>>(zreg, cb, cnorm, cidx);
  vq_select<<<NN / 64, 256, 0, stream>>>(zreg, cb, cidx, sel);
  vq_finish<<<NN / BM, 256, 0, stream>>>(cb, w_out, b_out, sel, out, loss_acc);
  vq_finalize<<<1, 1, 0, stream>>>(loss_acc, out);
}

// Round 7
// 165.007 us; speedup vs baseline: 2.1703x; 2.1703x over previous
//
#include <hip/hip_runtime.h>

#define CC 64      // channels
#define SS 16384   // D*W*H
#define NN 65536   // B*S tokens
#define KK 2048    // codebook size
#define BM 64      // tokens per block tile (conv/finish)
#define BMA 128    // tokens per argmin block

typedef __attribute__((ext_vector_type(8))) short bf16x8_t;
typedef __attribute__((ext_vector_type(4))) float fx4_t;
#define MFMA16 __builtin_amdgcn_mfma_f32_16x16x32_bf16

__device__ __forceinline__ unsigned short f2bf(float f) {
  unsigned u = __builtin_bit_cast(unsigned, f);
  return (unsigned short)((u + 0x7fff + ((u >> 16) & 1)) >> 16);  // RNE
}
__device__ __forceinline__ float bf2f(unsigned short h) {
  unsigned u = (unsigned)h << 16;
  return __builtin_bit_cast(float, u);
}
__device__ __forceinline__ void glds16(const void* g, void* l) {
  __builtin_amdgcn_global_load_lds(
      (const __attribute__((address_space(1))) unsigned*)g,
      (__attribute__((address_space(3))) unsigned*)l, 16, 0, 0);
}

// ============ kernel 1: pre = W_in @ x + b_in (fp64 accum, 4x4 tile) =====
__global__ __launch_bounds__(256, 4) void vq_conv_in(
    const float* __restrict__ x, const float* __restrict__ w_in,
    const float* __restrict__ b_in, float* __restrict__ xf) {
  __shared__ float xs[CC][BM];
  __shared__ float wt[CC][CC];
  int t = threadIdx.x;
  int n0 = blockIdx.x * BM;
  int b = n0 >> 14, s0 = n0 & (SS - 1);
  {
    int o = t >> 2, c0 = (t & 3) * 16;
    const float4* wr = (const float4*)(w_in + o * CC + c0);
#pragma unroll
    for (int i = 0; i < 4; ++i) {
      float4 v = wr[i];
      int ci = c0 + 4 * i;
      wt[ci + 0][o] = v.x; wt[ci + 1][o] = v.y;
      wt[ci + 2][o] = v.z; wt[ci + 3][o] = v.w;
    }
  }
#pragma unroll
  for (int i = 0; i < 4; ++i) {
    int e4 = t + 256 * i;
    int ci = e4 >> 4, tok4 = (e4 & 15) * 4;
    *(float4*)&xs[ci][tok4] =
        *(const float4*)(x + (size_t)b * CC * SS + (size_t)ci * SS + s0 + tok4);
  }
  __syncthreads();
  int tx = t & 15, ty = t >> 4;
  double acc[4][4];
#pragma unroll
  for (int j = 0; j < 4; ++j) {
    double bj = (double)b_in[tx * 4 + j];
#pragma unroll
    for (int m = 0; m < 4; ++m) acc[m][j] = bj;
  }
#pragma unroll 8
  for (int ci = 0; ci < CC; ++ci) {
    float4 xq = *(const float4*)&xs[ci][ty * 4];
    float4 wq = *(const float4*)&wt[ci][tx * 4];
    double xm[4] = {xq.x, xq.y, xq.z, xq.w};
    double wm[4] = {wq.x, wq.y, wq.z, wq.w};
#pragma unroll
    for (int m = 0; m < 4; ++m)
#pragma unroll
      for (int j = 0; j < 4; ++j) acc[m][j] = fma(xm[m], wm[j], acc[m][j]);
  }
#pragma unroll
  for (int j = 0; j < 4; ++j) {
    float4 ov = make_float4((float)acc[0][j], (float)acc[1][j],
                            (float)acc[2][j], (float)acc[3][j]);
    *(float4*)(xf + (size_t)b * CC * SS + (size_t)(tx * 4 + j) * SS + s0 +
               ty * 4) = ov;
  }
}

// ===== kernel 2: split codebook to bf16 hi/lo + ch = -0.5*||c||^2 =======
__global__ __launch_bounds__(256) void vq_split(
    const float* __restrict__ cb, unsigned short* __restrict__ cbh,
    unsigned short* __restrict__ cbl, float* __restrict__ ch) {
  int k = blockIdx.x * 256 + threadIdx.x;
  const float4* r = (const float4*)(cb + (size_t)k * CC);
  unsigned* oh = (unsigned*)(cbh + (size_t)k * CC);
  unsigned* ol = (unsigned*)(cbl + (size_t)k * CC);
  float s = 0.f;
#pragma unroll
  for (int i = 0; i < 16; ++i) {
    float4 v = r[i];
    float vv[4] = {v.x, v.y, v.z, v.w};
    unsigned short h[4], l[4];
#pragma unroll
    for (int u = 0; u < 4; ++u) {
      s = fmaf(vv[u], vv[u], s);
      h[u] = f2bf(vv[u]);
      l[u] = f2bf(vv[u] - bf2f(h[u]));
    }
    oh[2 * i + 0] = (unsigned)h[0] | ((unsigned)h[1] << 16);
    oh[2 * i + 1] = (unsigned)h[2] | ((unsigned)h[3] << 16);
    ol[2 * i + 0] = (unsigned)l[0] | ((unsigned)l[1] << 16);
    ol[2 * i + 1] = (unsigned)l[2] | ((unsigned)l[3] << 16);
  }
  ch[k] = -0.5f * s;
}

// ====== kernel 3: MFMA bf16-split scan, exact global top-2 per token =====
// Block: 128 tokens (4 waves x 32), all 2048 codes in 64 tiles of 32.
// S = -0.5||c||^2 + x.c (4 bf16-split passes, err ~2e-5). A-frags in regs;
// B tiles double-buffered via global_load_lds w/ inverse-swizzled source.
// R6 bug: loop staging omitted the per-wave +w*1024 LDS dest offset ->
// races + stale garbage in codes 8..31 of every tile. Fixed here.
__global__ __launch_bounds__(256, 2) void vq_mfma_argmin(
    const float* __restrict__ xf, const unsigned short* __restrict__ cbh,
    const unsigned short* __restrict__ cbl, const float* __restrict__ ch,
    int* __restrict__ cidx) {
  __shared__ __align__(16) unsigned char smem[32768];
  int t = threadIdx.x;
  int n0 = blockIdx.x * BMA;
  int b = n0 >> 14, s0 = n0 & (SS - 1);
  // ---- phase A: stage x tile token-major bf16 hi/lo, XOR-swizzled ----
  {
    int tok4 = (t & 31) * 4;
    const float* base = xf + (size_t)b * CC * SS + s0 + tok4;
#pragma unroll
    for (int i = 0; i < 8; ++i) {
      int c = (t >> 5) + 8 * i;
      float4 v = *(const float4*)(base + (size_t)c * SS);
      float vv[4] = {v.x, v.y, v.z, v.w};
#pragma unroll
      for (int u = 0; u < 4; ++u) {
        int tok = tok4 + u;
        unsigned short hs = f2bf(vv[u]);
        unsigned short ls = f2bf(vv[u] - bf2f(hs));
        int ad = tok * 128 + ((2 * c) ^ ((tok & 7) << 4));
        *(unsigned short*)(smem + ad) = hs;
        *(unsigned short*)(smem + 16384 + ad) = ls;
      }
    }
  }
  __syncthreads();
  // ---- A-frags to registers: A[row=lane&15][k=8*(lane>>4)+j] ----
  int lane = t & 63, w = t >> 6;
  int col = lane & 15, quad = lane >> 4;
  bf16x8_t ah[2][2], al[2][2];
#pragma unroll
  for (int rt = 0; rt < 2; ++rt) {
#pragma unroll
    for (int kk = 0; kk < 2; ++kk) {
      int tok = w * 32 + rt * 16 + col;
      int ad = tok * 128 + ((kk * 64 + quad * 16) ^ ((tok & 7) << 4));
      ah[rt][kk] = *(const bf16x8_t*)(smem + ad);
      al[rt][kk] = *(const bf16x8_t*)(smem + 16384 + ad);
    }
  }
  __syncthreads();  // xa consumed; smem reused for B double-buffer
  float best[2][4], secd[2][4];
  int bi[2][4], si[2][4];
#pragma unroll
  for (int rt = 0; rt < 2; ++rt)
#pragma unroll
    for (int r = 0; r < 4; ++r) {
      best[rt][r] = -3.402823466e+38f; secd[rt][r] = -3.402823466e+38f;
      bi[rt][r] = 0; si[rt][r] = 0;
    }
  // per-lane source offset implementing inverse swizzle for glds
  int srcoff = (lane * 16) ^ (((lane >> 3) & 7) << 4);
  const unsigned char* gh = (const unsigned char*)cbh;
  const unsigned char* gl = (const unsigned char*)cbl;
  // prologue: stage tile 0 into buf0 (wave w covers 1KB group w of hi & lo)
  glds16(gh + w * 1024 + srcoff, smem + w * 1024);
  glds16(gl + w * 1024 + srcoff, smem + 4096 + w * 1024);
  __syncthreads();
  const int NT = KK / 32;
  for (int kt = 0; kt < NT; ++kt) {
    unsigned char* bufc = smem + (kt & 1) * 8192;
    unsigned char* bufn = smem + ((kt + 1) & 1) * 8192;
    if (kt + 1 < NT) {
      size_t gof = (size_t)(kt + 1) * 4096 + w * 1024 + srcoff;
      glds16(gh + gof, bufn + w * 1024);           // FIX: per-wave LDS slice
      glds16(gl + gof, bufn + 4096 + w * 1024);    // FIX: per-wave LDS slice
    }
    float cn0 = ch[kt * 32 + col];
    float cn1 = ch[kt * 32 + 16 + col];
#pragma unroll
    for (int sub = 0; sub < 2; ++sub) {
      int cbyte0 = (sub * 16 + col) * 128 + ((quad * 16) ^ ((col & 7) << 4));
      int cbyte1 = (sub * 16 + col) * 128 + ((64 + quad * 16) ^ ((col & 7) << 4));
      bf16x8_t bh0 = *(const bf16x8_t*)(bufc + cbyte0);
      bf16x8_t bh1 = *(const bf16x8_t*)(bufc + cbyte1);
      bf16x8_t bl0 = *(const bf16x8_t*)(bufc + 4096 + cbyte0);
      bf16x8_t bl1 = *(const bf16x8_t*)(bufc + 4096 + cbyte1);
      float cn = sub ? cn1 : cn0;
      int kbase = kt * 32 + sub * 16 + col;
#pragma unroll
      for (int rt = 0; rt < 2; ++rt) {
        fx4_t acc = {cn, cn, cn, cn};
        acc = MFMA16(al[rt][0], bl0, acc, 0, 0, 0);  // smallest term first
        acc = MFMA16(al[rt][1], bl1, acc, 0, 0, 0);
        acc = MFMA16(al[rt][0], bh0, acc, 0, 0, 0);
        acc = MFMA16(al[rt][1], bh1, acc, 0, 0, 0);
        acc = MFMA16(ah[rt][0], bl0, acc, 0, 0, 0);
        acc = MFMA16(ah[rt][1], bl1, acc, 0, 0, 0);
        acc = MFMA16(ah[rt][0], bh0, acc, 0, 0, 0);
        acc = MFMA16(ah[rt][1], bh1, acc, 0, 0, 0);
#pragma unroll
        for (int r = 0; r < 4; ++r) {
          float v = acc[r];
          if (v > best[rt][r]) {
            secd[rt][r] = best[rt][r]; si[rt][r] = bi[rt][r];
            best[rt][r] = v; bi[rt][r] = kbase;
          } else if (v > secd[rt][r]) {
            secd[rt][r] = v; si[rt][r] = kbase;
          }
        }
      }
    }
    __syncthreads();
  }
  // cross-lane merge over the 16 cols of each token row (lex: max S, min k)
#pragma unroll
  for (int step = 1; step <= 8; step <<= 1) {
#pragma unroll
    for (int rt = 0; rt < 2; ++rt)
#pragma unroll
      for (int r = 0; r < 4; ++r) {
        float ob = __shfl_xor(best[rt][r], step, 64);
        int oi = __shfl_xor(bi[rt][r], step, 64);
        float os = __shfl_xor(secd[rt][r], step, 64);
        int oj = __shfl_xor(si[rt][r], step, 64);
        bool oW = (ob > best[rt][r]) || (ob == best[rt][r] && oi < bi[rt][r]);
        float nb = oW ? ob : best[rt][r];
        int ni = oW ? oi : bi[rt][r];
        float lb = oW ? best[rt][r] : ob;
        int li = oW ? bi[rt][r] : oi;
        float ws = oW ? os : secd[rt][r];
        int wi = oW ? oj : si[rt][r];
        bool sW = (ws > lb) || (ws == lb && wi < li);
        best[rt][r] = nb; bi[rt][r] = ni;
        secd[rt][r] = sW ? ws : lb; si[rt][r] = sW ? wi : li;
      }
  }
  if (col == 0) {
#pragma unroll
    for (int rt = 0; rt < 2; ++rt)
#pragma unroll
      for (int r = 0; r < 4; ++r) {
        int token = n0 + w * 32 + rt * 16 + quad * 4 + r;
        cidx[token] = bi[rt][r];
        cidx[(size_t)NN + token] = si[rt][r];
      }
  }
}

// ============ kernel 4: exact fp64 select among 2 candidates ============
__global__ __launch_bounds__(256) void vq_select(
    const float* __restrict__ xf, const float* __restrict__ cb,
    const int* __restrict__ cidx, int* __restrict__ sel) {
  int t = threadIdx.x;
  int n = blockIdx.x * 128 + (t >> 1);
  int cand = t & 1;
  int b = n >> 14, s = n & (SS - 1);
  int kj = cidx[(size_t)cand * NN + n];
  const float* xp = xf + (size_t)b * CC * SS + s;
  const float* cp = cb + (size_t)kj * CC;
  double dj = 0.0;
#pragma unroll 8
  for (int c = 0; c < CC; ++c) {
    double df = (double)xp[(size_t)c * SS] - (double)cp[c];
    dj = fma(df, df, dj);
  }
  double od = __shfl_xor(dj, 1, 64);
  int ok = __shfl_xor(kj, 1, 64);
  if (od < dj || (od == dj && ok < kj)) { dj = od; kj = ok; }
  if (cand == 0) sel[n] = kj;
}

// ====== kernel 5: gather q, z-write, losses, conv_out (4x4 tile) ======
__global__ __launch_bounds__(256, 3) void vq_finish(
    const float* __restrict__ cb, const float* __restrict__ w_out,
    const float* __restrict__ b_out, const int* __restrict__ sel,
    float* __restrict__ dout, float* __restrict__ loss_acc) {
  __shared__ float qs[CC][BM];
  __shared__ float xs[CC][BM];
  __shared__ float wt[CC][CC];
  __shared__ int ids[BM];
  int t = threadIdx.x;
  int n0 = blockIdx.x * BM;
  int b = n0 >> 14, s0 = n0 & (SS - 1);
  float* zreg = dout + (size_t)NN * CC;
  if (t < BM) ids[t] = sel[n0 + t];
  {
    int o = t >> 2, c0 = (t & 3) * 16;
    const float4* wr = (const float4*)(w_out + o * CC + c0);
#pragma unroll
    for (int i = 0; i < 4; ++i) {
      float4 v = wr[i];
      int ci = c0 + 4 * i;
      wt[ci + 0][o] = v.x; wt[ci + 1][o] = v.y;
      wt[ci + 2][o] = v.z; wt[ci + 3][o] = v.w;
    }
  }
#pragma unroll
  for (int i = 0; i < 4; ++i) {
    int e4 = t + 256 * i;
    int ci = e4 >> 4, tok4 = (e4 & 15) * 4;
    *(float4*)&xs[ci][tok4] = *(const float4*)(zreg + (size_t)b * CC * SS +
                                               (size_t)ci * SS + s0 + tok4);
  }
  __syncthreads();
  {
    int tok = t >> 2, c0 = (t & 3) * 16;
    const float4* qr = (const float4*)(cb + (size_t)ids[tok] * CC + c0);
#pragma unroll
    for (int i = 0; i < 4; ++i) {
      float4 v = qr[i];
      int ch = c0 + 4 * i;
      qs[ch + 0][tok] = v.x; qs[ch + 1][tok] = v.y;
      qs[ch + 2][tok] = v.z; qs[ch + 3][tok] = v.w;
    }
  }
  __syncthreads();
  float lsum = 0.f;
#pragma unroll
  for (int i = 0; i < 4; ++i) {
    int e4 = t + 256 * i;
    int ci = e4 >> 4, tok4 = (e4 & 15) * 4;
    float4 qv = *(const float4*)&qs[ci][tok4];
    float4 xv = *(const float4*)&xs[ci][tok4];
    float dx = qv.x - xv.x, dy = qv.y - xv.y;
    float dz = qv.z - xv.z, dw = qv.w - xv.w;
    lsum = fmaf(dx, dx, lsum); lsum = fmaf(dy, dy, lsum);
    lsum = fmaf(dz, dz, lsum); lsum = fmaf(dw, dw, lsum);
    *(float4*)(zreg + (size_t)b * CC * SS + (size_t)ci * SS + s0 + tok4) = qv;
  }
  int tx = t & 15, ty = t >> 4;
  float acc[4][4];
#pragma unroll
  for (int j = 0; j < 4; ++j) {
    float bj = b_out[tx * 4 + j];
#pragma unroll
    for (int m = 0; m < 4; ++m) acc[m][j] = bj;
  }
#pragma unroll 8
  for (int ci = 0; ci < CC; ++ci) {
    float4 xq = *(const float4*)&qs[ci][ty * 4];
    float4 wq = *(const float4*)&wt[ci][tx * 4];
    float xm[4] = {xq.x, xq.y, xq.z, xq.w};
    float wm[4] = {wq.x, wq.y, wq.z, wq.w};
#pragma unroll
    for (int m = 0; m < 4; ++m)
#pragma unroll
      for (int j = 0; j < 4; ++j) acc[m][j] = fmaf(xm[m], wm[j], acc[m][j]);
  }
#pragma unroll
  for (int j = 0; j < 4; ++j) {
    float4 ov = make_float4(acc[0][j], acc[1][j], acc[2][j], acc[3][j]);
    *(float4*)(dout + (size_t)b * CC * SS + (size_t)(tx * 4 + j) * SS + s0 +
               ty * 4) = ov;
  }
#pragma unroll
  for (int off = 32; off > 0; off >>= 1) lsum += __shfl_down(lsum, off, 64);
  __shared__ float wsum[4];
  if ((t & 63) == 0) wsum[t >> 6] = lsum;
  __syncthreads();
  if (t == 0) atomicAdd(loss_acc, wsum[0] + wsum[1] + wsum[2] + wsum[3]);
}

// ============ kernel 6: finalize scalar losses ============
__global__ void vq_finalize(const float* __restrict__ loss_acc,
                            float* __restrict__ dout) {
  float l = loss_acc[0] * (1.0f / (float)((size_t)NN * CC));
  dout[(size_t)2 * NN * CC + 0] = l;  // codebook_loss
  dout[(size_t)2 * NN * CC + 1] = l;  // commitment_loss
}

extern "C" void kernel_launch(void* const* d_in, const int* in_sizes, int n_in,
                              void* d_out, int out_size, void* d_ws,
                              size_t ws_size, hipStream_t stream) {
  const float* x = (const float*)d_in[0];
  const float* cb = (const float*)d_in[1];
  const float* w_in = (const float*)d_in[2];
  const float* b_in = (const float*)d_in[3];
  const float* w_out = (const float*)d_in[4];
  const float* b_out = (const float*)d_in[5];
  float* out = (float*)d_out;
  float* zreg = out + (size_t)NN * CC;  // z region doubles as xf scratch

  // ws: [0,4) loss; [1024,9216) ch; [16K,272K) cbh; [272K,528K) cbl;
  //     [528K,1040K) cidx(2xNN); [1040K,1296K) sel
  float* loss_acc = (float*)d_ws;
  float* ch = (float*)((char*)d_ws + 1024);
  unsigned short* cbh = (unsigned short*)((char*)d_ws + 16384);
  unsigned short* cbl = (unsigned short*)((char*)d_ws + 16384 + 262144);
  int* cidx = (int*)((char*)d_ws + 16384 + 2 * 262144);
  int* sel = (int*)((char*)d_ws + 16384 + 2 * 262144 + 524288);

  hipMemsetAsync(d_ws, 0, 4, stream);

  vq_conv_in<<<NN / BM, 256, 0, stream>>>(x, w_in, b_in, zreg);
  vq_split<<<KK / 256, 256, 0, stream>>>(cb, cbh, cbl, ch);
  vq_mfma_argmin<<<NN / BMA, 256, 0, stream>>>(zreg, cbh, cbl, ch, cidx);
  vq_select<<<NN / 128, 256, 0, stream>>>(zreg, cb, cidx, sel);
  vq_finish<<<NN / BM, 256, 0, stream>>>(cb, w_out, b_out, sel, out, loss_acc);
  vq_finalize<<<1, 1, 0, stream>>>(loss_acc, out);
}

// Round 8
// 132.687 us; speedup vs baseline: 2.6990x; 1.2436x over previous
//
#include <hip/hip_runtime.h>

#define CC 64      // channels
#define SS 16384   // D*W*H
#define NN 65536   // B*S tokens
#define KK 2048    // codebook size
#define BM 64      // tokens per block tile (conv/finish)
#define BMA 128    // tokens per argmin block

typedef __attribute__((ext_vector_type(8))) short bf16x8_t;
typedef __attribute__((ext_vector_type(4))) float fx4_t;
#define MFMA16 __builtin_amdgcn_mfma_f32_16x16x32_bf16

__device__ __forceinline__ unsigned short f2bf(float f) {
  unsigned u = __builtin_bit_cast(unsigned, f);
  return (unsigned short)((u + 0x7fff + ((u >> 16) & 1)) >> 16);  // RNE
}
__device__ __forceinline__ float bf2f(unsigned short h) {
  unsigned u = (unsigned)h << 16;
  return __builtin_bit_cast(float, u);
}
__device__ __forceinline__ void glds16(const void* g, void* l) {
  __builtin_amdgcn_global_load_lds(
      (const __attribute__((address_space(1))) unsigned*)g,
      (__attribute__((address_space(3))) unsigned*)l, 16, 0, 0);
}

// ============ kernel 1: pre = W_in @ x + b_in (fp64 accum, 4x4 tile) =====
__global__ __launch_bounds__(256, 4) void vq_conv_in(
    const float* __restrict__ x, const float* __restrict__ w_in,
    const float* __restrict__ b_in, float* __restrict__ xf) {
  __shared__ float xs[CC][BM];
  __shared__ float wt[CC][CC];
  int t = threadIdx.x;
  int n0 = blockIdx.x * BM;
  int b = n0 >> 14, s0 = n0 & (SS - 1);
  {
    int o = t >> 2, c0 = (t & 3) * 16;
    const float4* wr = (const float4*)(w_in + o * CC + c0);
#pragma unroll
    for (int i = 0; i < 4; ++i) {
      float4 v = wr[i];
      int ci = c0 + 4 * i;
      wt[ci + 0][o] = v.x; wt[ci + 1][o] = v.y;
      wt[ci + 2][o] = v.z; wt[ci + 3][o] = v.w;
    }
  }
#pragma unroll
  for (int i = 0; i < 4; ++i) {
    int e4 = t + 256 * i;
    int ci = e4 >> 4, tok4 = (e4 & 15) * 4;
    *(float4*)&xs[ci][tok4] =
        *(const float4*)(x + (size_t)b * CC * SS + (size_t)ci * SS + s0 + tok4);
  }
  __syncthreads();
  int tx = t & 15, ty = t >> 4;
  double acc[4][4];
#pragma unroll
  for (int j = 0; j < 4; ++j) {
    double bj = (double)b_in[tx * 4 + j];
#pragma unroll
    for (int m = 0; m < 4; ++m) acc[m][j] = bj;
  }
#pragma unroll 8
  for (int ci = 0; ci < CC; ++ci) {
    float4 xq = *(const float4*)&xs[ci][ty * 4];
    float4 wq = *(const float4*)&wt[ci][tx * 4];
    double xm[4] = {xq.x, xq.y, xq.z, xq.w};
    double wm[4] = {wq.x, wq.y, wq.z, wq.w};
#pragma unroll
    for (int m = 0; m < 4; ++m)
#pragma unroll
      for (int j = 0; j < 4; ++j) acc[m][j] = fma(xm[m], wm[j], acc[m][j]);
  }
#pragma unroll
  for (int j = 0; j < 4; ++j) {
    float4 ov = make_float4((float)acc[0][j], (float)acc[1][j],
                            (float)acc[2][j], (float)acc[3][j]);
    *(float4*)(xf + (size_t)b * CC * SS + (size_t)(tx * 4 + j) * SS + s0 +
               ty * 4) = ov;
  }
}

// ===== kernel 2: split codebook to bf16 hi/lo + ch = -0.5*||c||^2 =======
__global__ __launch_bounds__(256) void vq_split(
    const float* __restrict__ cb, unsigned short* __restrict__ cbh,
    unsigned short* __restrict__ cbl, float* __restrict__ ch) {
  int k = blockIdx.x * 256 + threadIdx.x;
  const float4* r = (const float4*)(cb + (size_t)k * CC);
  unsigned* oh = (unsigned*)(cbh + (size_t)k * CC);
  unsigned* ol = (unsigned*)(cbl + (size_t)k * CC);
  float s = 0.f;
#pragma unroll
  for (int i = 0; i < 16; ++i) {
    float4 v = r[i];
    float vv[4] = {v.x, v.y, v.z, v.w};
    unsigned short h[4], l[4];
#pragma unroll
    for (int u = 0; u < 4; ++u) {
      s = fmaf(vv[u], vv[u], s);
      h[u] = f2bf(vv[u]);
      l[u] = f2bf(vv[u] - bf2f(h[u]));
    }
    oh[2 * i + 0] = (unsigned)h[0] | ((unsigned)h[1] << 16);
    oh[2 * i + 1] = (unsigned)h[2] | ((unsigned)h[3] << 16);
    ol[2 * i + 0] = (unsigned)l[0] | ((unsigned)l[1] << 16);
    ol[2 * i + 1] = (unsigned)l[2] | ((unsigned)l[3] << 16);
  }
  ch[k] = -0.5f * s;
}

// ====== kernel 3: MFMA bf16-split scan, K-split x2, top-2 per half =======
// blockIdx bit0 = K-half (1024 codes); rest = 128-token group. 4 waves,
// wave w owns 32 tokens (2 rt). 16 tiles of 64 codes, double-buffered via
// global_load_lds w/ inverse-swizzled source. 3 MFMA passes (hh+hl+lh; ll
// dropped: ~1e-5 err, caught by top-2 + fp64 re-rank). Phase A writes
// packed bf16x8 via ds_write_b128 (throughput-optimal under swizzle).
__global__ __launch_bounds__(256, 4) void vq_mfma_argmin(
    const float* __restrict__ xf, const unsigned short* __restrict__ cbh,
    const unsigned short* __restrict__ cbl, const float* __restrict__ ch,
    int* __restrict__ cidx) {
  __shared__ __align__(16) unsigned char smem[32768];
  int t = threadIdx.x;
  int kh = blockIdx.x & 1;
  int n0 = (blockIdx.x >> 1) * BMA;
  int b = n0 >> 14, s0 = n0 & (SS - 1);
  // ---- phase A: thread-per-token staging, b128 swizzled stores ----
  {
    int tok = t & 127;
    int half = t >> 7;  // channel half 0..1 (32 ch each)
    const float* xb = xf + (size_t)b * CC * SS + s0 + tok;
#pragma unroll
    for (int i = 0; i < 4; ++i) {
      int c0 = half * 32 + i * 8;
      bf16x8_t h8, l8;
#pragma unroll
      for (int j = 0; j < 8; ++j) {
        float v = xb[(size_t)(c0 + j) * SS];
        unsigned short hs = f2bf(v);
        h8[j] = (short)hs;
        l8[j] = (short)f2bf(v - bf2f(hs));
      }
      int ad = tok * 128 + ((half * 64 + i * 16) ^ ((tok & 7) << 4));
      *(bf16x8_t*)(smem + ad) = h8;
      *(bf16x8_t*)(smem + 16384 + ad) = l8;
    }
  }
  __syncthreads();
  // ---- A-frags to registers ----
  int lane = t & 63, w = t >> 6;
  int col = lane & 15, quad = lane >> 4;
  bf16x8_t ah[2][2], al[2][2];
#pragma unroll
  for (int rt = 0; rt < 2; ++rt) {
#pragma unroll
    for (int kk = 0; kk < 2; ++kk) {
      int tok = w * 32 + rt * 16 + col;
      int ad = tok * 128 + ((kk * 64 + quad * 16) ^ ((tok & 7) << 4));
      ah[rt][kk] = *(const bf16x8_t*)(smem + ad);
      al[rt][kk] = *(const bf16x8_t*)(smem + 16384 + ad);
    }
  }
  __syncthreads();  // x consumed; smem becomes B double-buffer (2 x 16KB)
  float best[2][4], secd[2][4];
  int bi[2][4], si[2][4];
#pragma unroll
  for (int rt = 0; rt < 2; ++rt)
#pragma unroll
    for (int r = 0; r < 4; ++r) {
      best[rt][r] = -3.402823466e+38f; secd[rt][r] = -3.402823466e+38f;
      bi[rt][r] = 0; si[rt][r] = 0;
    }
  int srcoff = (lane * 16) ^ (((lane >> 3) & 7) << 4);  // inverse swizzle
  const unsigned char* ghh =
      (const unsigned char*)cbh + (size_t)kh * 1024 * 128;
  const unsigned char* glh =
      (const unsigned char*)cbl + (size_t)kh * 1024 * 128;
  // prologue: stage tile 0 (64 codes: hi 8KB + lo 8KB; wave w -> 2KB each)
  glds16(ghh + w * 2048 + srcoff, smem + w * 2048);
  glds16(ghh + w * 2048 + 1024 + srcoff, smem + w * 2048 + 1024);
  glds16(glh + w * 2048 + srcoff, smem + 8192 + w * 2048);
  glds16(glh + w * 2048 + 1024 + srcoff, smem + 8192 + w * 2048 + 1024);
  __syncthreads();
  const int NT = 16;  // 16 tiles x 64 codes = 1024 codes per half
  for (int kt = 0; kt < NT; ++kt) {
    unsigned char* bufc = smem + (kt & 1) * 16384;
    unsigned char* bufn = smem + ((kt + 1) & 1) * 16384;
    if (kt + 1 < NT) {
      size_t gof = (size_t)(kt + 1) * 8192 + w * 2048 + srcoff;
      glds16(ghh + gof, bufn + w * 2048);
      glds16(ghh + gof + 1024, bufn + w * 2048 + 1024);
      glds16(glh + gof, bufn + 8192 + w * 2048);
      glds16(glh + gof + 1024, bufn + 8192 + w * 2048 + 1024);
    }
    int kb = kh * 1024 + kt * 64;
#pragma unroll
    for (int sub = 0; sub < 4; ++sub) {
      int row = sub * 16 + col;
      int swz = (col & 7) << 4;
      int cb0 = row * 128 + ((quad * 16) ^ swz);
      int cb1 = row * 128 + ((64 + quad * 16) ^ swz);
      bf16x8_t bh0 = *(const bf16x8_t*)(bufc + cb0);
      bf16x8_t bh1 = *(const bf16x8_t*)(bufc + cb1);
      bf16x8_t bl0 = *(const bf16x8_t*)(bufc + 8192 + cb0);
      bf16x8_t bl1 = *(const bf16x8_t*)(bufc + 8192 + cb1);
      float cn = ch[kb + sub * 16 + col];
      int kbase = kb + sub * 16 + col;
#pragma unroll
      for (int rt = 0; rt < 2; ++rt) {
        fx4_t acc = {cn, cn, cn, cn};
        acc = MFMA16(al[rt][0], bh0, acc, 0, 0, 0);  // lh
        acc = MFMA16(al[rt][1], bh1, acc, 0, 0, 0);
        acc = MFMA16(ah[rt][0], bl0, acc, 0, 0, 0);  // hl
        acc = MFMA16(ah[rt][1], bl1, acc, 0, 0, 0);
        acc = MFMA16(ah[rt][0], bh0, acc, 0, 0, 0);  // hh
        acc = MFMA16(ah[rt][1], bh1, acc, 0, 0, 0);
#pragma unroll
        for (int r = 0; r < 4; ++r) {
          float v = acc[r];
          if (v > best[rt][r]) {
            secd[rt][r] = best[rt][r]; si[rt][r] = bi[rt][r];
            best[rt][r] = v; bi[rt][r] = kbase;
          } else if (v > secd[rt][r]) {
            secd[rt][r] = v; si[rt][r] = kbase;
          }
        }
      }
    }
    __syncthreads();
  }
  // cross-lane merge over the 16 cols of each token row (lex: max S, min k)
#pragma unroll
  for (int step = 1; step <= 8; step <<= 1) {
#pragma unroll
    for (int rt = 0; rt < 2; ++rt)
#pragma unroll
      for (int r = 0; r < 4; ++r) {
        float ob = __shfl_xor(best[rt][r], step, 64);
        int oi = __shfl_xor(bi[rt][r], step, 64);
        float os = __shfl_xor(secd[rt][r], step, 64);
        int oj = __shfl_xor(si[rt][r], step, 64);
        bool oW = (ob > best[rt][r]) || (ob == best[rt][r] && oi < bi[rt][r]);
        float nb = oW ? ob : best[rt][r];
        int ni = oW ? oi : bi[rt][r];
        float lb = oW ? best[rt][r] : ob;
        int li = oW ? bi[rt][r] : oi;
        float ws = oW ? os : secd[rt][r];
        int wi = oW ? oj : si[rt][r];
        bool sW = (ws > lb) || (ws == lb && wi < li);
        best[rt][r] = nb; bi[rt][r] = ni;
        secd[rt][r] = sW ? ws : lb; si[rt][r] = sW ? wi : li;
      }
  }
  if (col == 0) {
#pragma unroll
    for (int rt = 0; rt < 2; ++rt)
#pragma unroll
      for (int r = 0; r < 4; ++r) {
        int token = n0 + w * 32 + rt * 16 + quad * 4 + r;
        cidx[(size_t)(2 * kh + 0) * NN + token] = bi[rt][r];
        cidx[(size_t)(2 * kh + 1) * NN + token] = si[rt][r];
      }
  }
}

// ============ kernel 4: exact fp64 select among 4 candidates ============
__global__ __launch_bounds__(256) void vq_select(
    const float* __restrict__ xf, const float* __restrict__ cb,
    const int* __restrict__ cidx, int* __restrict__ sel) {
  int t = threadIdx.x;
  int n = blockIdx.x * 64 + (t >> 2);
  int cand = t & 3;
  int b = n >> 14, s = n & (SS - 1);
  int kj = cidx[(size_t)cand * NN + n];
  const float* xp = xf + (size_t)b * CC * SS + s;
  const float* cp = cb + (size_t)kj * CC;
  double dj = 0.0;
#pragma unroll 8
  for (int c = 0; c < CC; ++c) {
    double df = (double)xp[(size_t)c * SS] - (double)cp[c];
    dj = fma(df, df, dj);
  }
#pragma unroll
  for (int step = 1; step <= 2; step <<= 1) {
    double od = __shfl_xor(dj, step, 64);
    int ok = __shfl_xor(kj, step, 64);
    if (od < dj || (od == dj && ok < kj)) { dj = od; kj = ok; }
  }
  if (cand == 0) sel[n] = kj;
}

// ====== kernel 5: gather q, z-write, losses, conv_out (4x4 tile) ======
__global__ __launch_bounds__(256, 3) void vq_finish(
    const float* __restrict__ cb, const float* __restrict__ w_out,
    const float* __restrict__ b_out, const int* __restrict__ sel,
    float* __restrict__ dout, float* __restrict__ loss_acc) {
  __shared__ float qs[CC][BM];
  __shared__ float xs[CC][BM];
  __shared__ float wt[CC][CC];
  __shared__ int ids[BM];
  int t = threadIdx.x;
  int n0 = blockIdx.x * BM;
  int b = n0 >> 14, s0 = n0 & (SS - 1);
  float* zreg = dout + (size_t)NN * CC;
  if (t < BM) ids[t] = sel[n0 + t];
  {
    int o = t >> 2, c0 = (t & 3) * 16;
    const float4* wr = (const float4*)(w_out + o * CC + c0);
#pragma unroll
    for (int i = 0; i < 4; ++i) {
      float4 v = wr[i];
      int ci = c0 + 4 * i;
      wt[ci + 0][o] = v.x; wt[ci + 1][o] = v.y;
      wt[ci + 2][o] = v.z; wt[ci + 3][o] = v.w;
    }
  }
#pragma unroll
  for (int i = 0; i < 4; ++i) {
    int e4 = t + 256 * i;
    int ci = e4 >> 4, tok4 = (e4 & 15) * 4;
    *(float4*)&xs[ci][tok4] = *(const float4*)(zreg + (size_t)b * CC * SS +
                                               (size_t)ci * SS + s0 + tok4);
  }
  __syncthreads();
  {
    int tok = t >> 2, c0 = (t & 3) * 16;
    const float4* qr = (const float4*)(cb + (size_t)ids[tok] * CC + c0);
#pragma unroll
    for (int i = 0; i < 4; ++i) {
      float4 v = qr[i];
      int ch = c0 + 4 * i;
      qs[ch + 0][tok] = v.x; qs[ch + 1][tok] = v.y;
      qs[ch + 2][tok] = v.z; qs[ch + 3][tok] = v.w;
    }
  }
  __syncthreads();
  float lsum = 0.f;
#pragma unroll
  for (int i = 0; i < 4; ++i) {
    int e4 = t + 256 * i;
    int ci = e4 >> 4, tok4 = (e4 & 15) * 4;
    float4 qv = *(const float4*)&qs[ci][tok4];
    float4 xv = *(const float4*)&xs[ci][tok4];
    float dx = qv.x - xv.x, dy = qv.y - xv.y;
    float dz = qv.z - xv.z, dw = qv.w - xv.w;
    lsum = fmaf(dx, dx, lsum); lsum = fmaf(dy, dy, lsum);
    lsum = fmaf(dz, dz, lsum); lsum = fmaf(dw, dw, lsum);
    *(float4*)(zreg + (size_t)b * CC * SS + (size_t)ci * SS + s0 + tok4) = qv;
  }
  int tx = t & 15, ty = t >> 4;
  float acc[4][4];
#pragma unroll
  for (int j = 0; j < 4; ++j) {
    float bj = b_out[tx * 4 + j];
#pragma unroll
    for (int m = 0; m < 4; ++m) acc[m][j] = bj;
  }
#pragma unroll 8
  for (int ci = 0; ci < CC; ++ci) {
    float4 xq = *(const float4*)&qs[ci][ty * 4];
    float4 wq = *(const float4*)&wt[ci][tx * 4];
    float xm[4] = {xq.x, xq.y, xq.z, xq.w};
    float wm[4] = {wq.x, wq.y, wq.z, wq.w};
#pragma unroll
    for (int m = 0; m < 4; ++m)
#pragma unroll
      for (int j = 0; j < 4; ++j) acc[m][j] = fmaf(xm[m], wm[j], acc[m][j]);
  }
#pragma unroll
  for (int j = 0; j < 4; ++j) {
    float4 ov = make_float4(acc[0][j], acc[1][j], acc[2][j], acc[3][j]);
    *(float4*)(dout + (size_t)b * CC * SS + (size_t)(tx * 4 + j) * SS + s0 +
               ty * 4) = ov;
  }
#pragma unroll
  for (int off = 32; off > 0; off >>= 1) lsum += __shfl_down(lsum, off, 64);
  __shared__ float wsum[4];
  if ((t & 63) == 0) wsum[t >> 6] = lsum;
  __syncthreads();
  if (t == 0) atomicAdd(loss_acc, wsum[0] + wsum[1] + wsum[2] + wsum[3]);
}

// ============ kernel 6: finalize scalar losses ============
__global__ void vq_finalize(const float* __restrict__ loss_acc,
                            float* __restrict__ dout) {
  float l = loss_acc[0] * (1.0f / (float)((size_t)NN * CC));
  dout[(size_t)2 * NN * CC + 0] = l;  // codebook_loss
  dout[(size_t)2 * NN * CC + 1] = l;  // commitment_loss
}

extern "C" void kernel_launch(void* const* d_in, const int* in_sizes, int n_in,
                              void* d_out, int out_size, void* d_ws,
                              size_t ws_size, hipStream_t stream) {
  const float* x = (const float*)d_in[0];
  const float* cb = (const float*)d_in[1];
  const float* w_in = (const float*)d_in[2];
  const float* b_in = (const float*)d_in[3];
  const float* w_out = (const float*)d_in[4];
  const float* b_out = (const float*)d_in[5];
  float* out = (float*)d_out;
  float* zreg = out + (size_t)NN * CC;  // z region doubles as xf scratch

  // ws: [0,4) loss; [1024,9216) ch; [16K,272K) cbh; [272K,528K) cbl;
  //     [528K,1552K) cidx(4xNN); [1552K,1808K) sel
  float* loss_acc = (float*)d_ws;
  float* ch = (float*)((char*)d_ws + 1024);
  unsigned short* cbh = (unsigned short*)((char*)d_ws + 16384);
  unsigned short* cbl = (unsigned short*)((char*)d_ws + 16384 + 262144);
  int* cidx = (int*)((char*)d_ws + 16384 + 2 * 262144);
  int* sel = (int*)((char*)d_ws + 16384 + 2 * 262144 + 4 * NN * 4);

  hipMemsetAsync(d_ws, 0, 4, stream);

  vq_conv_in<<<NN / BM, 256, 0, stream>>>(x, w_in, b_in, zreg);
  vq_split<<<KK / 256, 256, 0, stream>>>(cb, cbh, cbl, ch);
  vq_mfma_argmin<<<(NN / BMA) * 2, 256, 0, stream>>>(zreg, cbh, cbl, ch, cidx);
  vq_select<<<NN / 64, 256, 0, stream>>>(zreg, cb, cidx, sel);
  vq_finish<<<NN / BM, 256, 0, stream>>>(cb, w_out, b_out, sel, out, loss_acc);
  vq_finalize<<<1, 1, 0, stream>>>(loss_acc, out);
}